// Round 12
// baseline (75.264 us; speedup 1.0000x reference)
//
#include <hip/hip_runtime.h>
#include <math.h>

#define NB 2
#define QN 8192
#define DIM 256
#define S_TOT 5440   // 4096+1024+256+64

typedef unsigned int uint32;
typedef _Float16 f16;
typedef __attribute__((ext_vector_type(8))) _Float16 h8;   // MFMA A/B frag (4 VGPR)
typedef __attribute__((ext_vector_type(2))) _Float16 h2;
typedef __attribute__((ext_vector_type(4))) float f32x4;   // MFMA C/D frag

// Fragment-linear layout: element (row s, col k) of a [S][256] f16 matrix lives
// at  ((s>>4)*32 + (k>>3))*128 + (s&15)*8 + (k&7).
// A wave's MFMA fragment load (16 rows x 8 k) is then base + lane*16B: coalesced.

// ---------------------------------------------------------------------------
// prep: query f32 -> qf (frag f16); feat -> featT_f (transpose+frag);
//       weights -> Wcat_f/Wval_f/Wout_f (transpose+frag). ONE launch.
// grid.x: [0,128) query (y = row-subtile), [128,468) feat tiles, [468,496) W.
// ---------------------------------------------------------------------------
__global__ __launch_bounds__(256) void prep_kernel(
    const float* __restrict__ q,
    const float* __restrict__ f0, const float* __restrict__ f1,
    const float* __restrict__ f2, const float* __restrict__ f3,
    const float* __restrict__ W_off, const float* __restrict__ W_attn,
    const float* __restrict__ W_val, const float* __restrict__ W_out,
    f16* __restrict__ qf, f16* __restrict__ featT_f,
    f16* __restrict__ Wcat_f, f16* __restrict__ Wval_f, f16* __restrict__ Wout_f) {
  const int t = blockIdx.x, y = blockIdx.y, tid = threadIdx.x;

  if (t < 128) {
    // ---- query: 16 rows x 256 cols per (t,y) ----
    const int row0 = (t * 8 + y) * 16;
    const int s_l = tid >> 4, c8 = tid & 15;
    const float* src = q + (size_t)(row0 + s_l) * 256;
#pragma unroll
    for (int cc = 0; cc < 2; ++cc) {
      const int c8c = c8 + cc * 16;
      const float4 u0 = *(const float4*)(src + c8c * 8);
      const float4 u1 = *(const float4*)(src + c8c * 8 + 4);
      h8 hv = {(f16)u0.x, (f16)u0.y, (f16)u0.z, (f16)u0.w,
               (f16)u1.x, (f16)u1.y, (f16)u1.z, (f16)u1.w};
      *(h8*)(qf + ((size_t)(row0 >> 4) * 32 + c8c) * 128 + s_l * 8) = hv;
    }
    return;
  }

  __shared__ float tile[32][33];
  const int tx = tid & 31, ty = tid >> 5;
  const float* src;
  f16* dst;
  int S, tb, s_base = 0;

  if (t < 468) {
    // ---- feat transpose tiles ----
    const int tt0 = t - 128;
    const int b = (tt0 >= 170) ? 1 : 0;
    const int tt = tt0 - 170 * b;
    int soff;
    if (tt < 128)      { src = f0; S = 4096; soff = 0;    tb = tt; }
    else if (tt < 160) { src = f1; S = 1024; soff = 4096; tb = tt - 128; }
    else if (tt < 168) { src = f2; S = 256;  soff = 5120; tb = tt - 160; }
    else               { src = f3; S = 64;   soff = 5376; tb = tt - 168; }
    src += (size_t)b * 256 * S;
    dst = featT_f;
    s_base = b * S_TOT + soff;
  } else {
    // ---- weight transpose tiles ----
    const int tw = t - 468;
    if (tw < 8)       { src = W_off;  dst = Wcat_f; S = 256; tb = tw;      s_base = 0; }
    else if (tw < 12) { src = W_attn; dst = Wcat_f; S = 128; tb = tw - 8;  s_base = 256; }
    else if (tw < 20) { src = W_val;  dst = Wval_f; S = 256; tb = tw - 12; s_base = 0; }
    else              { src = W_out;  dst = Wout_f; S = 256; tb = tw - 20; s_base = 0; }
  }
  const int s0 = tb * 32, c0 = y * 32;

#pragma unroll
  for (int j = 0; j < 4; ++j) {
    const int c = c0 + ty + j * 8;
    tile[ty + j * 8][tx] = src[(size_t)c * S + s0 + tx];
  }
  __syncthreads();

  if (tid < 128) {
    const int s_l = tid >> 2, c8l = tid & 3;
    const int Sg = s_base + s0 + s_l;
    const int c8 = (c0 >> 3) + c8l;
    h8 v;
#pragma unroll
    for (int j = 0; j < 8; ++j) v[j] = (f16)tile[c8l * 8 + j][s_l];
    *(h8*)(dst + ((size_t)(Sg >> 4) * 32 + c8) * 128 + (Sg & 15) * 8) = v;
  }
}

// ---------------------------------------------------------------------------
// Fused GEMM, zero LDS / zero barriers, frag-linear operands.
// blocks [0,340): vals[t*32..+32) = featT @ Wval + b_val (wave: 64 cols)
// blocks [340,852): offb/attnb = query @ Wcat + bias     (wave: 96 cols)
// ---------------------------------------------------------------------------
__global__ __launch_bounds__(256) void gemm_fused_kernel(
    const f16* __restrict__ qf, const f16* __restrict__ featT_f,
    const f16* __restrict__ Wcat_f, const f16* __restrict__ Wval_f,
    const float* __restrict__ b_val, const float* __restrict__ b_off,
    const float* __restrict__ b_attn,
    f16* __restrict__ vals, f16* __restrict__ offb, f16* __restrict__ attnb) {
  const int t = blockIdx.x;
  const int tid = threadIdx.x;
  const int lane = tid & 63, wid = tid >> 6;
  const int l15 = lane & 15, l4 = lane >> 4;

  if (t < 340) {
    const int g0 = t * 2;
    f32x4 acc[2][4] = {};
#pragma unroll
    for (int ks = 0; ks < 8; ++ks) {
      const int s2 = ks * 4 + l4;
      h8 a[2], b[4];
#pragma unroll
      for (int m = 0; m < 2; ++m)
        a[m] = *(const h8*)(featT_f + ((size_t)(g0 + m) * 32 + s2) * 128 + l15 * 8);
#pragma unroll
      for (int n = 0; n < 4; ++n)
        b[n] = *(const h8*)(Wval_f + ((size_t)(wid * 4 + n) * 32 + s2) * 128 + l15 * 8);
#pragma unroll
      for (int m = 0; m < 2; ++m)
#pragma unroll
        for (int n = 0; n < 4; ++n)
          acc[m][n] = __builtin_amdgcn_mfma_f32_16x16x32_f16(a[m], b[n], acc[m][n], 0, 0, 0);
    }
#pragma unroll
    for (int m = 0; m < 2; ++m)
#pragma unroll
      for (int n = 0; n < 4; ++n)
#pragma unroll
        for (int r = 0; r < 4; ++r) {
          const size_t rw = (size_t)t * 32 + m * 16 + l4 * 4 + r;
          const int col = wid * 64 + n * 16 + l15;
          vals[rw * 256 + col] = (f16)(acc[m][n][r] + b_val[col]);
        }
  } else {
    const int t2 = t - 340;
    const int g0 = t2 * 2;
    f32x4 acc[2][6] = {};
#pragma unroll
    for (int ks = 0; ks < 8; ++ks) {
      const int s2 = ks * 4 + l4;
      h8 a[2], b[6];
#pragma unroll
      for (int m = 0; m < 2; ++m)
        a[m] = *(const h8*)(qf + ((size_t)(g0 + m) * 32 + s2) * 128 + l15 * 8);
#pragma unroll
      for (int n = 0; n < 6; ++n)
        b[n] = *(const h8*)(Wcat_f + ((size_t)(wid * 6 + n) * 32 + s2) * 128 + l15 * 8);
#pragma unroll
      for (int m = 0; m < 2; ++m)
#pragma unroll
        for (int n = 0; n < 6; ++n)
          acc[m][n] = __builtin_amdgcn_mfma_f32_16x16x32_f16(a[m], b[n], acc[m][n], 0, 0, 0);
    }
#pragma unroll
    for (int m = 0; m < 2; ++m)
#pragma unroll
      for (int n = 0; n < 6; ++n)
#pragma unroll
        for (int r = 0; r < 4; ++r) {
          const size_t rw = (size_t)t2 * 32 + m * 16 + l4 * 4 + r;
          const int col = wid * 96 + n * 16 + l15;
          const float v = acc[m][n][r];
          if (col < 256)
            offb[rw * 256 + col] = (f16)(v + b_off[col]);
          else
            attnb[rw * 128 + (col - 256)] = (f16)(v + b_attn[col - 256]);
        }
  }
}

// ---------------------------------------------------------------------------
// Out projection, zero LDS / zero barriers: samp_f (frag) @ Wout_f (frag).
// 512 blocks x 32 rows; wave wid owns 64 cols.
// ---------------------------------------------------------------------------
__global__ __launch_bounds__(256) void gemm_out_kernel(
    const f16* __restrict__ A, const f16* __restrict__ Bt,
    const float* __restrict__ bias, float* __restrict__ out) {
  const int tid = threadIdx.x;
  const int lane = tid & 63, wid = tid >> 6;
  const int l15 = lane & 15, l4 = lane >> 4;
  const int g0 = blockIdx.x * 2;

  f32x4 acc[2][4] = {};
#pragma unroll
  for (int ks = 0; ks < 8; ++ks) {
    const int s2 = ks * 4 + l4;
    h8 a[2], b[4];
#pragma unroll
    for (int m = 0; m < 2; ++m)
      a[m] = *(const h8*)(A + ((size_t)(g0 + m) * 32 + s2) * 128 + l15 * 8);
#pragma unroll
    for (int n = 0; n < 4; ++n)
      b[n] = *(const h8*)(Bt + ((size_t)(wid * 4 + n) * 32 + s2) * 128 + l15 * 8);
#pragma unroll
    for (int m = 0; m < 2; ++m)
#pragma unroll
      for (int n = 0; n < 4; ++n)
        acc[m][n] = __builtin_amdgcn_mfma_f32_16x16x32_f16(a[m], b[n], acc[m][n], 0, 0, 0);
  }

#pragma unroll
  for (int m = 0; m < 2; ++m)
#pragma unroll
    for (int n = 0; n < 4; ++n)
#pragma unroll
      for (int r = 0; r < 4; ++r) {
        const size_t rw = (size_t)blockIdx.x * 32 + m * 16 + l4 * 4 + r;
        const int col = wid * 64 + n * 16 + l15;
        out[rw * 256 + col] = acc[m][n][r] + bias[col];
      }
}

// ---------------------------------------------------------------------------
// Sampling + softmax + weighted sum — occupancy-first restructure.
// ONE query per block (16384 blocks), 256 threads:
//   grp = tid>>4: h = grp>>1 (head), ph = grp&1 (point-half).
//   lane g = tid&15: c4 = g&3 (channel octet), pc = g>>2 (corner).
// Phase 1 (tid<128): thread (h = tid>>4, pt = tid&15) computes softmax weight
//   + bilinear params once -> LDS (4 KB).
// Phase 2: each lane gathers 8 points (vv[8] = 32 VGPR -> ~80 total,
//   ~6 waves/SIMD vs ~3 before), fp32 fma, reduce: shfl_xor 4 (corner),
//   8 (corner), 16 (point-half). Writers: pc==0 && ph==0.
// Output stored fragment-linear for the zero-barrier out projection.
// ---------------------------------------------------------------------------
__global__ __launch_bounds__(256) void sample_kernel(
    const f16* __restrict__ vals, const f16* __restrict__ offb,
    const f16* __restrict__ attnb, const float* __restrict__ refp,
    f16* __restrict__ samp_f) {
  const int tid = threadIdx.x;
  const int bq = blockIdx.x;
  const int b = bq >> 13;

  __shared__ float4 wts[8][16];
  __shared__ int4 idxs[8][16];

  // ---- phase 1: params for all 8 heads x 16 points of this query ----
  if (tid < 128) {
    const int h = tid >> 4, pt = tid & 15;
    const float rx = refp[(size_t)bq * 2 + 0];
    const float ry = refp[(size_t)bq * 2 + 1];

    float logit = (float)attnb[(size_t)bq * 128 + tid];
    float m = logit;
#pragma unroll
    for (int mask = 1; mask < 16; mask <<= 1)
      m = fmaxf(m, __shfl_xor(m, mask, 16));
    const float e = __expf(logit - m);
    float ssum = e;
#pragma unroll
    for (int mask = 1; mask < 16; mask <<= 1)
      ssum += __shfl_xor(ssum, mask, 16);
    const float aw = e / ssum;

    const h2 ov = *(const h2*)(offb + (size_t)bq * 256 + h * 32 + pt * 2);
    const int l = pt >> 2;
    const int Wl = 64 >> l;
    const int loff = (l == 0) ? 0 : (l == 1) ? 4096 : (l == 2) ? 5120 : 5376;

    const float px = (rx + (float)ov[0]) * (float)Wl - 0.5f;
    const float py = (ry + (float)ov[1]) * (float)Wl - 0.5f;
    const float fx = floorf(px), fy = floorf(py);
    const float wx = px - fx, wy = py - fy;
    const int x0 = (int)fx, y0 = (int)fy;
    const int x1 = x0 + 1, y1 = y0 + 1;
    const float vx0 = (x0 >= 0 && x0 < Wl) ? 1.f : 0.f;
    const float vx1 = (x1 >= 0 && x1 < Wl) ? 1.f : 0.f;
    const float vy0 = (y0 >= 0 && y0 < Wl) ? 1.f : 0.f;
    const float vy1 = (y1 >= 0 && y1 < Wl) ? 1.f : 0.f;
    const int cx0 = min(max(x0, 0), Wl - 1), cx1 = min(max(x1, 0), Wl - 1);
    const int cy0 = min(max(y0, 0), Wl - 1), cy1 = min(max(y1, 0), Wl - 1);
    const int base = b * S_TOT + loff;
    idxs[h][pt] = make_int4((base + cy0 * Wl + cx0) * 512,
                            (base + cy0 * Wl + cx1) * 512,
                            (base + cy1 * Wl + cx0) * 512,
                            (base + cy1 * Wl + cx1) * 512);
    wts[h][pt] = make_float4(aw * (1.f - wx) * (1.f - wy) * vx0 * vy0,
                             aw * wx * (1.f - wy) * vx1 * vy0,
                             aw * (1.f - wx) * wy * vx0 * vy1,
                             aw * wx * wy * vx1 * vy1);
  }
  __syncthreads();

  // ---- phase 2: 8 gathers per lane ----
  const int grp = tid >> 4, g = tid & 15;
  const int h = grp >> 1, ph = grp & 1;
  const int c4 = g & 3, pc = g >> 2;
  const char* vb = (const char*)vals + (h * 64 + c4 * 16);

  float wv[8];
  int ids[8];
#pragma unroll
  for (int i = 0; i < 8; ++i) {
    const int pt = ph * 8 + i;
    wv[i] = ((const float*)&wts[h][pt])[pc];
    ids[i] = ((const int*)&idxs[h][pt])[pc];
  }
  h8 vv[8];
#pragma unroll
  for (int i = 0; i < 8; ++i) vv[i] = *(const h8*)(vb + ids[i]);

  float a[8] = {};
#pragma unroll
  for (int i = 0; i < 8; ++i) {
#pragma unroll
    for (int k = 0; k < 8; ++k) a[k] = fmaf((float)vv[i][k], wv[i], a[k]);
  }
#pragma unroll
  for (int k = 0; k < 8; ++k) {
    a[k] += __shfl_xor(a[k], 4);    // corner bit 0
    a[k] += __shfl_xor(a[k], 8);    // corner bit 1
    a[k] += __shfl_xor(a[k], 16);   // point-half
  }
  if (pc == 0 && ph == 0) {
    h8 r;
#pragma unroll
    for (int k = 0; k < 8; ++k) r[k] = (f16)a[k];
    // frag-linear store: row bq, cols [h*32+c4*8 .. +8)
    *(h8*)(samp_f + ((size_t)(bq >> 4) * 32 + h * 4 + c4) * 128 + (bq & 15) * 8) = r;
  }
}

// ---------------------------------------------------------------------------
extern "C" void kernel_launch(void* const* d_in, const int* in_sizes, int n_in,
                              void* d_out, int out_size, void* d_ws, size_t ws_size,
                              hipStream_t stream) {
  const float* query = (const float*)d_in[0];
  const float* feat[4] = {(const float*)d_in[1], (const float*)d_in[2],
                          (const float*)d_in[3], (const float*)d_in[4]};
  const float* refp  = (const float*)d_in[5];
  const float* W_off = (const float*)d_in[6];
  const float* b_off = (const float*)d_in[7];
  const float* W_attn = (const float*)d_in[8];
  const float* b_attn = (const float*)d_in[9];
  const float* W_val = (const float*)d_in[10];
  const float* b_val = (const float*)d_in[11];
  const float* W_out = (const float*)d_in[12];
  const float* b_out = (const float*)d_in[13];
  float* out = (float*)d_out;

  // ---- workspace layout (f16 units; ~32.6 MB) ----
  f16* ws = (f16*)d_ws;
  f16* vals    = ws;                                  // [10880][256] linear 5.57MB
  f16* offb    = vals + (size_t)NB * S_TOT * 256;     // [16384][256] linear 8.4MB
  f16* attnb   = offb + (size_t)NB * QN * 256;        // [16384][128] linear 4.2MB
  f16* qf      = attnb + (size_t)NB * QN * 128;       // [16384][256] frag   8.4MB
  f16* samp_f  = qf;                                  // ALIAS: sample writes after
                                                      // gemm_fused consumed qf
  f16* featT_f = qf + (size_t)NB * QN * 256;          // [10880][256] frag   5.57MB
  f16* Wcat_f  = featT_f + (size_t)NB * S_TOT * 256;  // [384][256] frag
  f16* Wval_f  = Wcat_f + 384 * 256;                  // [256][256] frag
  f16* Wout_f  = Wval_f + 256 * 256;                  // [256][256] frag

  // 1. all conversions/permutes in one launch
  prep_kernel<<<dim3(496, 8), 256, 0, stream>>>(
      query, feat[0], feat[1], feat[2], feat[3],
      W_off, W_attn, W_val, W_out, qf, featT_f, Wcat_f, Wval_f, Wout_f);

  // 2. value proj + offset/logit proj (zero-barrier streaming MFMA)
  gemm_fused_kernel<<<340 + 512, 256, 0, stream>>>(
      qf, featT_f, Wcat_f, Wval_f, b_val, b_off, b_attn, vals, offb, attnb);

  // 3. sampling -> samp_f (frag layout; overwrites qf region)
  sample_kernel<<<NB * QN, 256, 0, stream>>>(vals, offb, attnb, refp, samp_f);

  // 4. out projection (zero-barrier streaming MFMA) -> d_out f32
  gemm_out_kernel<<<(NB * QN) / 32, 256, 0, stream>>>(samp_f, Wout_f, b_out, out);
}

// Round 13
// 68.198 us; speedup vs baseline: 1.1036x; 1.1036x over previous
//
#include <hip/hip_runtime.h>
#include <math.h>

#define NB 2
#define QN 8192
#define DIM 256
#define S_TOT 5440   // 4096+1024+256+64

typedef unsigned int uint32;
typedef _Float16 f16;
typedef __attribute__((ext_vector_type(8))) _Float16 h8;   // MFMA A/B frag (4 VGPR)
typedef __attribute__((ext_vector_type(2))) _Float16 h2;
typedef __attribute__((ext_vector_type(4))) float f32x4;   // MFMA C/D frag

__device__ __forceinline__ h2 shfl_h2(h2 v, int mask) {
  union { h2 h; int i; } u; u.h = v;
  u.i = __shfl_xor(u.i, mask);
  return u.h;
}
__device__ __forceinline__ int pack_h2(float w) {
  union { h2 h; int i; } u; const f16 wh = (f16)w; u.h = h2{wh, wh};
  return u.i;
}

// Fragment-linear layout: element (row s, col k) of a [S][256] f16 matrix lives
// at  ((s>>4)*32 + (k>>3))*128 + (s&15)*8 + (k&7).
// A wave's MFMA fragment load (16 rows x 8 k) is then base + lane*16B: coalesced.

// ---------------------------------------------------------------------------
// prep: query f32 -> qf (frag f16); feat -> featT_f (transpose+frag);
//       weights -> Wcat_f/Wval_f/Wout_f (transpose+frag). ONE launch.
// grid.x: [0,128) query (y = row-subtile), [128,468) feat tiles, [468,496) W.
// ---------------------------------------------------------------------------
__global__ __launch_bounds__(256) void prep_kernel(
    const float* __restrict__ q,
    const float* __restrict__ f0, const float* __restrict__ f1,
    const float* __restrict__ f2, const float* __restrict__ f3,
    const float* __restrict__ W_off, const float* __restrict__ W_attn,
    const float* __restrict__ W_val, const float* __restrict__ W_out,
    f16* __restrict__ qf, f16* __restrict__ featT_f,
    f16* __restrict__ Wcat_f, f16* __restrict__ Wval_f, f16* __restrict__ Wout_f) {
  const int t = blockIdx.x, y = blockIdx.y, tid = threadIdx.x;

  if (t < 128) {
    // ---- query: 16 rows x 256 cols per (t,y) ----
    const int row0 = (t * 8 + y) * 16;
    const int s_l = tid >> 4, c8 = tid & 15;
    const float* src = q + (size_t)(row0 + s_l) * 256;
#pragma unroll
    for (int cc = 0; cc < 2; ++cc) {
      const int c8c = c8 + cc * 16;
      const float4 u0 = *(const float4*)(src + c8c * 8);
      const float4 u1 = *(const float4*)(src + c8c * 8 + 4);
      h8 hv = {(f16)u0.x, (f16)u0.y, (f16)u0.z, (f16)u0.w,
               (f16)u1.x, (f16)u1.y, (f16)u1.z, (f16)u1.w};
      *(h8*)(qf + ((size_t)(row0 >> 4) * 32 + c8c) * 128 + s_l * 8) = hv;
    }
    return;
  }

  __shared__ float tile[32][33];
  const int tx = tid & 31, ty = tid >> 5;
  const float* src;
  f16* dst;
  int S, tb, s_base = 0;

  if (t < 468) {
    // ---- feat transpose tiles ----
    const int tt0 = t - 128;
    const int b = (tt0 >= 170) ? 1 : 0;
    const int tt = tt0 - 170 * b;
    int soff;
    if (tt < 128)      { src = f0; S = 4096; soff = 0;    tb = tt; }
    else if (tt < 160) { src = f1; S = 1024; soff = 4096; tb = tt - 128; }
    else if (tt < 168) { src = f2; S = 256;  soff = 5120; tb = tt - 160; }
    else               { src = f3; S = 64;   soff = 5376; tb = tt - 168; }
    src += (size_t)b * 256 * S;
    dst = featT_f;
    s_base = b * S_TOT + soff;
  } else {
    // ---- weight transpose tiles ----
    const int tw = t - 468;
    if (tw < 8)       { src = W_off;  dst = Wcat_f; S = 256; tb = tw;      s_base = 0; }
    else if (tw < 12) { src = W_attn; dst = Wcat_f; S = 128; tb = tw - 8;  s_base = 256; }
    else if (tw < 20) { src = W_val;  dst = Wval_f; S = 256; tb = tw - 12; s_base = 0; }
    else              { src = W_out;  dst = Wout_f; S = 256; tb = tw - 20; s_base = 0; }
  }
  const int s0 = tb * 32, c0 = y * 32;

#pragma unroll
  for (int j = 0; j < 4; ++j) {
    const int c = c0 + ty + j * 8;
    tile[ty + j * 8][tx] = src[(size_t)c * S + s0 + tx];
  }
  __syncthreads();

  if (tid < 128) {
    const int s_l = tid >> 2, c8l = tid & 3;
    const int Sg = s_base + s0 + s_l;
    const int c8 = (c0 >> 3) + c8l;
    h8 v;
#pragma unroll
    for (int j = 0; j < 8; ++j) v[j] = (f16)tile[c8l * 8 + j][s_l];
    *(h8*)(dst + ((size_t)(Sg >> 4) * 32 + c8) * 128 + (Sg & 15) * 8) = v;
  }
}

// ---------------------------------------------------------------------------
// Fused GEMM, zero LDS / zero barriers, frag-linear operands.
// blocks [0,340): vals[t*32..+32) = featT @ Wval + b_val (wave: 64 cols)
// blocks [340,852): offb/attnb = query @ Wcat + bias     (wave: 96 cols)
// ---------------------------------------------------------------------------
__global__ __launch_bounds__(256) void gemm_fused_kernel(
    const f16* __restrict__ qf, const f16* __restrict__ featT_f,
    const f16* __restrict__ Wcat_f, const f16* __restrict__ Wval_f,
    const float* __restrict__ b_val, const float* __restrict__ b_off,
    const float* __restrict__ b_attn,
    f16* __restrict__ vals, f16* __restrict__ offb, f16* __restrict__ attnb) {
  const int t = blockIdx.x;
  const int tid = threadIdx.x;
  const int lane = tid & 63, wid = tid >> 6;
  const int l15 = lane & 15, l4 = lane >> 4;

  if (t < 340) {
    const int g0 = t * 2;
    f32x4 acc[2][4] = {};
#pragma unroll
    for (int ks = 0; ks < 8; ++ks) {
      const int s2 = ks * 4 + l4;
      h8 a[2], b[4];
#pragma unroll
      for (int m = 0; m < 2; ++m)
        a[m] = *(const h8*)(featT_f + ((size_t)(g0 + m) * 32 + s2) * 128 + l15 * 8);
#pragma unroll
      for (int n = 0; n < 4; ++n)
        b[n] = *(const h8*)(Wval_f + ((size_t)(wid * 4 + n) * 32 + s2) * 128 + l15 * 8);
#pragma unroll
      for (int m = 0; m < 2; ++m)
#pragma unroll
        for (int n = 0; n < 4; ++n)
          acc[m][n] = __builtin_amdgcn_mfma_f32_16x16x32_f16(a[m], b[n], acc[m][n], 0, 0, 0);
    }
#pragma unroll
    for (int m = 0; m < 2; ++m)
#pragma unroll
      for (int n = 0; n < 4; ++n)
#pragma unroll
        for (int r = 0; r < 4; ++r) {
          const size_t rw = (size_t)t * 32 + m * 16 + l4 * 4 + r;
          const int col = wid * 64 + n * 16 + l15;
          vals[rw * 256 + col] = (f16)(acc[m][n][r] + b_val[col]);
        }
  } else {
    const int t2 = t - 340;
    const int g0 = t2 * 2;
    f32x4 acc[2][6] = {};
#pragma unroll
    for (int ks = 0; ks < 8; ++ks) {
      const int s2 = ks * 4 + l4;
      h8 a[2], b[6];
#pragma unroll
      for (int m = 0; m < 2; ++m)
        a[m] = *(const h8*)(qf + ((size_t)(g0 + m) * 32 + s2) * 128 + l15 * 8);
#pragma unroll
      for (int n = 0; n < 6; ++n)
        b[n] = *(const h8*)(Wcat_f + ((size_t)(wid * 6 + n) * 32 + s2) * 128 + l15 * 8);
#pragma unroll
      for (int m = 0; m < 2; ++m)
#pragma unroll
        for (int n = 0; n < 6; ++n)
          acc[m][n] = __builtin_amdgcn_mfma_f32_16x16x32_f16(a[m], b[n], acc[m][n], 0, 0, 0);
    }
#pragma unroll
    for (int m = 0; m < 2; ++m)
#pragma unroll
      for (int n = 0; n < 6; ++n)
#pragma unroll
        for (int r = 0; r < 4; ++r) {
          const size_t rw = (size_t)t2 * 32 + m * 16 + l4 * 4 + r;
          const int col = wid * 96 + n * 16 + l15;
          const float v = acc[m][n][r];
          if (col < 256)
            offb[rw * 256 + col] = (f16)(v + b_off[col]);
          else
            attnb[rw * 128 + (col - 256)] = (f16)(v + b_attn[col - 256]);
        }
  }
}

// ---------------------------------------------------------------------------
// Out projection, zero LDS / zero barriers: samp_f (frag) @ Wout_f (frag).
// 512 blocks x 32 rows; wave wid owns 64 cols.
// ---------------------------------------------------------------------------
__global__ __launch_bounds__(256) void gemm_out_kernel(
    const f16* __restrict__ A, const f16* __restrict__ Bt,
    const float* __restrict__ bias, float* __restrict__ out) {
  const int tid = threadIdx.x;
  const int lane = tid & 63, wid = tid >> 6;
  const int l15 = lane & 15, l4 = lane >> 4;
  const int g0 = blockIdx.x * 2;

  f32x4 acc[2][4] = {};
#pragma unroll
  for (int ks = 0; ks < 8; ++ks) {
    const int s2 = ks * 4 + l4;
    h8 a[2], b[4];
#pragma unroll
    for (int m = 0; m < 2; ++m)
      a[m] = *(const h8*)(A + ((size_t)(g0 + m) * 32 + s2) * 128 + l15 * 8);
#pragma unroll
    for (int n = 0; n < 4; ++n)
      b[n] = *(const h8*)(Bt + ((size_t)(wid * 4 + n) * 32 + s2) * 128 + l15 * 8);
#pragma unroll
    for (int m = 0; m < 2; ++m)
#pragma unroll
      for (int n = 0; n < 4; ++n)
        acc[m][n] = __builtin_amdgcn_mfma_f32_16x16x32_f16(a[m], b[n], acc[m][n], 0, 0, 0);
  }

#pragma unroll
  for (int m = 0; m < 2; ++m)
#pragma unroll
    for (int n = 0; n < 4; ++n)
#pragma unroll
      for (int r = 0; r < 4; ++r) {
        const size_t rw = (size_t)blockIdx.x * 32 + m * 16 + l4 * 4 + r;
        const int col = wid * 64 + n * 16 + l15;
        out[rw * 256 + col] = acc[m][n][r] + bias[col];
      }
}

// ---------------------------------------------------------------------------
// Sampling + softmax + weighted sum — packed-f16 MAC (no cvts).
// Block = 2 queries; per query 8 heads x 16 lanes (grp).
// Phase 1: lane g = point g: softmax weight + bilinear params; stores
//          pre-packed h2{w,w} corner weights (int4) + byte offsets (int4)
//          to padded LDS ([16][17] -> conflict-free phase-2 reads).
// Phase 2: lane (c4=g&3, pc=g>>2): channels 8*c4..8*c4+7, corner pc.
//          16 gathers issued back-to-back (MLP=16); 4 v_pk_fma_f16 per point
//          (h2 accumulators, 32 VALU total vs 128 with f32 cvt+fma);
//          packed shfl_xor(4|8) corner reduce; pc==0 stores h8 frag-linear.
// ---------------------------------------------------------------------------
__global__ __launch_bounds__(256) void sample_kernel(
    const f16* __restrict__ vals, const f16* __restrict__ offb,
    const f16* __restrict__ attnb, const float* __restrict__ refp,
    f16* __restrict__ samp_f) {
  const int tid = threadIdx.x;
  const int g = tid & 15;
  const int grp = tid >> 4;
  const int h = grp & 7;
  const int half = tid >> 7;
  const int bq = blockIdx.x * 2 + half;
  const int b = bq >> 13;

  __shared__ int4 wts2[16][17];   // packed h2{w,w} per corner
  __shared__ int4 idxs[16][17];   // byte offsets per corner

  // ---- phase 1 ----
  const float rx = refp[(size_t)bq * 2 + 0];
  const float ry = refp[(size_t)bq * 2 + 1];

  float logit = (float)attnb[(size_t)bq * 128 + h * 16 + g];
  float m = logit;
#pragma unroll
  for (int mask = 1; mask < 16; mask <<= 1)
    m = fmaxf(m, __shfl_xor(m, mask, 16));
  const float e = __expf(logit - m);
  float ssum = e;
#pragma unroll
  for (int mask = 1; mask < 16; mask <<= 1)
    ssum += __shfl_xor(ssum, mask, 16);
  const float aw = e / ssum;

  const h2 ov = *(const h2*)(offb + (size_t)bq * 256 + h * 32 + g * 2);
  const int l = g >> 2;
  const int Wl = 64 >> l;
  const int loff = (l == 0) ? 0 : (l == 1) ? 4096 : (l == 2) ? 5120 : 5376;

  const float px = (rx + (float)ov[0]) * (float)Wl - 0.5f;
  const float py = (ry + (float)ov[1]) * (float)Wl - 0.5f;
  const float fx = floorf(px), fy = floorf(py);
  const float wx = px - fx, wy = py - fy;
  const int x0 = (int)fx, y0 = (int)fy;
  const int x1 = x0 + 1, y1 = y0 + 1;
  const float vx0 = (x0 >= 0 && x0 < Wl) ? 1.f : 0.f;
  const float vx1 = (x1 >= 0 && x1 < Wl) ? 1.f : 0.f;
  const float vy0 = (y0 >= 0 && y0 < Wl) ? 1.f : 0.f;
  const float vy1 = (y1 >= 0 && y1 < Wl) ? 1.f : 0.f;
  const int cx0 = min(max(x0, 0), Wl - 1), cx1 = min(max(x1, 0), Wl - 1);
  const int cy0 = min(max(y0, 0), Wl - 1), cy1 = min(max(y1, 0), Wl - 1);
  const int base = b * S_TOT + loff;
  idxs[grp][g] = make_int4((base + cy0 * Wl + cx0) * 512,
                           (base + cy0 * Wl + cx1) * 512,
                           (base + cy1 * Wl + cx0) * 512,
                           (base + cy1 * Wl + cx1) * 512);
  wts2[grp][g] = make_int4(pack_h2(aw * (1.f - wx) * (1.f - wy) * vx0 * vy0),
                           pack_h2(aw * wx * (1.f - wy) * vx1 * vy0),
                           pack_h2(aw * (1.f - wx) * wy * vx0 * vy1),
                           pack_h2(aw * wx * wy * vx1 * vy1));
  __syncthreads();

  // ---- phase 2 ----
  const int c4 = g & 3, pc = g >> 2;
  const char* vb = (const char*)vals + (h * 64 + c4 * 16);

  int wv[16];
  int ids[16];
#pragma unroll
  for (int pt = 0; pt < 16; ++pt) {
    wv[pt] = ((const int*)&wts2[grp][pt])[pc];
    ids[pt] = ((const int*)&idxs[grp][pt])[pc];
  }
  h8 vv[16];
#pragma unroll
  for (int pt = 0; pt < 16; ++pt) vv[pt] = *(const h8*)(vb + ids[pt]);

  h2 a2[4] = {};
#pragma unroll
  for (int pt = 0; pt < 16; ++pt) {
    union { int i; h2 h; } w; w.i = wv[pt];
    const h2* vp = (const h2*)&vv[pt];
    a2[0] += vp[0] * w.h;
    a2[1] += vp[1] * w.h;
    a2[2] += vp[2] * w.h;
    a2[3] += vp[3] * w.h;
  }
#pragma unroll
  for (int j = 0; j < 4; ++j) {
    a2[j] += shfl_h2(a2[j], 4);
    a2[j] += shfl_h2(a2[j], 8);
  }
  if (pc == 0) {
    h8 r = {a2[0][0], a2[0][1], a2[1][0], a2[1][1],
            a2[2][0], a2[2][1], a2[3][0], a2[3][1]};
    // frag-linear store: row bq, cols [h*32+c4*8 .. +8)
    *(h8*)(samp_f + ((size_t)(bq >> 4) * 32 + h * 4 + c4) * 128 + (bq & 15) * 8) = r;
  }
}

// ---------------------------------------------------------------------------
extern "C" void kernel_launch(void* const* d_in, const int* in_sizes, int n_in,
                              void* d_out, int out_size, void* d_ws, size_t ws_size,
                              hipStream_t stream) {
  const float* query = (const float*)d_in[0];
  const float* feat[4] = {(const float*)d_in[1], (const float*)d_in[2],
                          (const float*)d_in[3], (const float*)d_in[4]};
  const float* refp  = (const float*)d_in[5];
  const float* W_off = (const float*)d_in[6];
  const float* b_off = (const float*)d_in[7];
  const float* W_attn = (const float*)d_in[8];
  const float* b_attn = (const float*)d_in[9];
  const float* W_val = (const float*)d_in[10];
  const float* b_val = (const float*)d_in[11];
  const float* W_out = (const float*)d_in[12];
  const float* b_out = (const float*)d_in[13];
  float* out = (float*)d_out;

  // ---- workspace layout (f16 units; ~32.6 MB) ----
  f16* ws = (f16*)d_ws;
  f16* vals    = ws;                                  // [10880][256] linear 5.57MB
  f16* offb    = vals + (size_t)NB * S_TOT * 256;     // [16384][256] linear 8.4MB
  f16* attnb   = offb + (size_t)NB * QN * 256;        // [16384][128] linear 4.2MB
  f16* qf      = attnb + (size_t)NB * QN * 128;       // [16384][256] frag   8.4MB
  f16* samp_f  = qf;                                  // ALIAS: sample writes after
                                                      // gemm_fused consumed qf
  f16* featT_f = qf + (size_t)NB * QN * 256;          // [10880][256] frag   5.57MB
  f16* Wcat_f  = featT_f + (size_t)NB * S_TOT * 256;  // [384][256] frag
  f16* Wval_f  = Wcat_f + 384 * 256;                  // [256][256] frag
  f16* Wout_f  = Wval_f + 256 * 256;                  // [256][256] frag

  // 1. all conversions/permutes in one launch
  prep_kernel<<<dim3(496, 8), 256, 0, stream>>>(
      query, feat[0], feat[1], feat[2], feat[3],
      W_off, W_attn, W_val, W_out, qf, featT_f, Wcat_f, Wval_f, Wout_f);

  // 2. value proj + offset/logit proj (zero-barrier streaming MFMA)
  gemm_fused_kernel<<<340 + 512, 256, 0, stream>>>(
      qf, featT_f, Wcat_f, Wval_f, b_val, b_off, b_attn, vals, offb, attnb);

  // 3. sampling -> samp_f (frag layout; overwrites qf region)
  sample_kernel<<<(NB * QN) / 2, 256, 0, stream>>>(vals, offb, attnb, refp, samp_f);

  // 4. out projection (zero-barrier streaming MFMA) -> d_out f32
  gemm_out_kernel<<<(NB * QN) / 32, 256, 0, stream>>>(samp_f, Wout_f, b_out, out);
}